// Round 21
// baseline (48.885 us; speedup 1.0000x reference)
//
#include <hip/hip_runtime.h>
#include <hip/hip_bf16.h>

#define NROWS 8192      // B*T
#define KDIM  768       // F_IN
#define VSZ   320       // V
#define GSZ   2         // G
#define NCOL  640       // G*V
#define DSZ   128       // D
#define BM    64        // rows per block
#define NMT   (NROWS / BM)             // 128 M-tiles
#define NBLK  (NMT * 2)                // 256 blocks (x2 group-halves)
#define NKB   24                       // K blocks of 32
#define XQ_TOTAL (NROWS * GSZ * DSZ)   // 2097152
#define MARGIN 0.75f    // 12 sigma of bf16-dot pairwise error (sigma ~0.062)

typedef __attribute__((ext_vector_type(8))) short bf16x8;
typedef __attribute__((ext_vector_type(4))) float f32x4;

static __device__ __forceinline__ short f2bf(float f) {
    union { __hip_bfloat16 h; short s; } u;
    u.h = __float2bfloat16(f);   // round-to-nearest-even
    return u.s;
}

static __device__ __forceinline__ void gload_lds16(const void* g, void* l) {
    __builtin_amdgcn_global_load_lds(
        (const __attribute__((address_space(1))) void*)g,
        (__attribute__((address_space(3))) void*)l, 16, 0, 0);
}

// ---------------- prep: pack W only (frag-major bf16); zero accf ----------------
__global__ __launch_bounds__(256) void prep_w_k(const float* __restrict__ W,
                                                short* __restrict__ Wb,
                                                float* __restrict__ accf) {
    if (blockIdx.x == 0) {
        for (int i = threadIdx.x; i < 2 * NCOL; i += 256) accf[i] = 0.f;
    }
    const int id   = blockIdx.x * 256 + threadIdx.x;   // 0..61439
    const int lane = id & 63;
    const int f    = id >> 6;                           // 0..959
    const int n    = f % 5;
    const int t2   = f / 5;
    const int hc   = t2 & 7;
    const int kb   = t2 >> 3;                           // 0..23
    const int col  = (hc * 5 + n) * 16 + (lane & 15);
    const int k    = kb * 32 + (lane >> 4) * 8;
    const float4 a = *(const float4*)(W + (size_t)col * KDIM + k);
    const float4 c = *(const float4*)(W + (size_t)col * KDIM + k + 4);
    bf16x8 r;
    r[0] = f2bf(a.x); r[1] = f2bf(a.y); r[2] = f2bf(a.z); r[3] = f2bf(a.w);
    r[4] = f2bf(c.x); r[5] = f2bf(c.y); r[6] = f2bf(c.z); r[7] = f2bf(c.w);
    *(bf16x8*)(Wb + (size_t)id * 8) = r;
}

// B staging for one 32-k step: 20 frags; each of 8 waves issues 3 gloads (uniform
// vmcnt); frags 16..19 double-issued (identical data -> benign).
#define STAGEB(kb32, BUF) do {                                                 \
    _Pragma("unroll")                                                          \
    for (int j = 0; j < 3; ++j) {                                              \
        const int rm = (j == 0) ? w : (j == 1) ? (w + 8) : (16 + (w & 3));     \
        const short* srcp = Wb + ((size_t)((kb32) * 8 + hc0 + rm / 5) * 5 + rm % 5) * 512; \
        gload_lds16(srcp + lane * 8, (char*)(BUF) + 4096 + rm * 1024);         \
    }                                                                          \
} while (0)

// A staging: thread owns (row = tid>>3, kk = (tid&7)*4); f32->bf16, 8B ds_write
#define AWRITE(BUF, v) do {                                                    \
    const short s0 = f2bf((v).x), s1 = f2bf((v).y);                            \
    const short s2 = f2bf((v).z), s3 = f2bf((v).w);                            \
    const int lo = (s0 & 0xffff) | ((int)s1 << 16);                            \
    const int hi = (s2 & 0xffff) | ((int)s3 << 16);                            \
    *(int2*)((char*)(BUF) + a_off) = make_int2(lo, hi);                        \
} while (0)

// Wave tile 32x80: acc[hh][n]; reads 2 A + 5 B frags, 10 MFMA per 32-k step.
#define COMPUTE(BUF) do {                                                      \
    const char* _bp = (const char*)(BUF);                                      \
    const bf16x8 a0 = *(const bf16x8*)(_bp + (rs * 2 + 0) * 1024 + lane * 16); \
    const bf16x8 a1 = *(const bf16x8*)(_bp + (rs * 2 + 1) * 1024 + lane * 16); \
    bf16x8 bb[5];                                                              \
    _Pragma("unroll")                                                          \
    for (int n = 0; n < 5; ++n)                                                \
        bb[n] = *(const bf16x8*)(_bp + 4096 + (cc * 5 + n) * 1024 + lane * 16);\
    _Pragma("unroll")                                                          \
    for (int n = 0; n < 5; ++n) {                                              \
        acc[0][n] = __builtin_amdgcn_mfma_f32_16x16x32_bf16(a0, bb[n], acc[0][n], 0, 0, 0); \
        acc[1][n] = __builtin_amdgcn_mfma_f32_16x16x32_bf16(a1, bb[n], acc[1][n], 0, 0, 0); \
    }                                                                          \
} while (0)

#define SYNC(N) do {                                                           \
    asm volatile("s_waitcnt vmcnt(" #N ") lgkmcnt(0)" ::: "memory");           \
    __builtin_amdgcn_sched_barrier(0);                                         \
    __builtin_amdgcn_s_barrier();                                              \
} while (0)

// Phase k: stage-first / A-write-last. Steady-state entry in-flight = {x(k+1)}.
// STAGEB(k+1) -> {x(k+1), s×3}; load x(k+2) -> 5; COMPUTE(k); AWRITE waits x(k+1)
// (oldest -> vmcnt(4), a full phase of slack); SYNC(1) drains s×3, leaves x(k+2).
#define PH(kk, BUFN, BUFC, XOLD, XNEW) do {                                    \
    STAGEB((kk) + 1, BUFN);                                                    \
    XNEW = *(const float4*)(xrow + ((kk) + 2) * 32);                           \
    COMPUTE(BUFC);                                                             \
    AWRITE(BUFN, XOLD);                                                        \
    SYNC(1);                                                                   \
} while (0)

// ---------------- fused: 2-buffer issue-early/write-late GEMM + epilogue ----------------
// grid 256 = 128 M-tiles x 2 groups (XCD-swizzled); 512 threads = 8 waves (rs x cc);
// LDS 61.5 KB -> 2 blocks/CU.
__global__ __launch_bounds__(512, 4) void fused_vq_k(
    const short* __restrict__ Wb,
    const float* __restrict__ x, const float* __restrict__ W,
    const float* __restrict__ b, const float* __restrict__ codebook,
    float* __restrict__ accf, float* __restrict__ xq) {

    __shared__ __align__(16) char bufs[2][24 * 1024];   // 49,152 B
    __shared__ float pacc[2][VSZ];
    __shared__ float cnt_f[VSZ];
    __shared__ float wmax[BM][4];
    __shared__ int   warg[BM][4];
    __shared__ float ssum[BM][4];
    __shared__ float rmax_s[BM];
    __shared__ int   rarg_s[BM];
    __shared__ int   cnt_s[BM];
    __shared__ int   list_s[BM][16];
    __shared__ int   code_s[BM];
    __shared__ int   work_s[BM];
    __shared__ int   nwork_s;

    const int tid   = threadIdx.x;
    const int lane  = tid & 63;
    const int w     = tid >> 6;       // wave 0..7
    const int l15   = lane & 15;
    const int l4    = lane >> 4;
    const int sb    = ((int)blockIdx.x & 7) * (NBLK / 8) + ((int)blockIdx.x >> 3);
    const int mt    = sb >> 1;
    const int h     = sb & 1;         // group
    const int row0  = mt * BM;
    const int rs    = w >> 2;         // row-set 0..1 (32 rows each)
    const int cc    = w & 3;          // col-chunk 0..3 (80 cols)
    const int hc0   = h * 4;
    const int nf0   = h * 20 + cc * 5;

    // A-staging thread ownership
    const int arow  = tid >> 3;           // 0..63
    const int akk   = (tid & 7) * 4;      // 0,4,..,28
    const int a_off = (arow >> 4) * 1024 + ((arow & 15) + 16 * (akk >> 3)) * 16 + (akk & 4) * 2;
    const float* xrow = x + (size_t)(row0 + arow) * KDIM + akk;

    for (int i = tid; i < VSZ; i += 512) cnt_f[i] = 0.f;
    if (tid < BM) cnt_s[tid] = 0;
    if (tid == 0) nwork_s = 0;

    char* B0 = bufs[0];
    char* B1 = bufs[1];

    f32x4 acc[2][5];
#pragma unroll
    for (int hh = 0; hh < 2; ++hh)
#pragma unroll
        for (int n = 0; n < 5; ++n) acc[hh][n] = (f32x4){0.f, 0.f, 0.f, 0.f};

    // ---- prologue ----
    float4 xv0, xv1;
    {
        const float4 t0 = *(const float4*)(xrow);    // x(0)
        AWRITE(B0, t0);                              // waits x(0) only
        STAGEB(0, B0);                               // s0 x3 in flight
        xv0 = *(const float4*)(xrow + 32);           // x(1) -> 4 in flight
        SYNC(1);                                     // drain s0, keep x(1)
    }

    // ---- main loop: 22 phases (k=0..21) as 11 two-phase trips ----
#pragma unroll 1
    for (int t = 0; t < 11; ++t) {
        PH(2 * t + 0, B1, B0, xv0, xv1);
        PH(2 * t + 1, B0, B1, xv1, xv0);
    }
    // phase 22: stage kb23, compute kb22; xv0 = x(23)
    STAGEB(23, B1);
    COMPUTE(B0);
    AWRITE(B1, xv0);                                 // waits x(23)
    SYNC(0);                                         // drain s23 + A-writes
    COMPUTE(B1);                                     // kb23

    // bias (zeros in this problem, kept exact)
#pragma unroll
    for (int n = 0; n < 5; ++n) {
        const float bv = b[(nf0 + n) * 16 + l15];
#pragma unroll
        for (int hh = 0; hh < 2; ++hh)
#pragma unroll
            for (int r = 0; r < 4; ++r) acc[hh][n][r] += bv;
    }

    // E1: wave-local per-row max/argmax; rows rs*32 + hh*16 + l4*4 + r
    float m4[2][4]; int a4[2][4];
#pragma unroll
    for (int hh = 0; hh < 2; ++hh)
#pragma unroll
        for (int r = 0; r < 4; ++r) { m4[hh][r] = -3.4e38f; a4[hh][r] = 0x7fffffff; }
#pragma unroll
    for (int n = 0; n < 5; ++n) {
        const int col = (nf0 + n) * 16 + l15;
#pragma unroll
        for (int hh = 0; hh < 2; ++hh)
#pragma unroll
            for (int r = 0; r < 4; ++r) {
                const float v = acc[hh][n][r];
                if (v > m4[hh][r]) { m4[hh][r] = v; a4[hh][r] = col; }
            }
    }
#pragma unroll
    for (int off = 8; off >= 1; off >>= 1)
#pragma unroll
        for (int hh = 0; hh < 2; ++hh)
#pragma unroll
            for (int r = 0; r < 4; ++r) {
                const float om = __shfl_xor(m4[hh][r], off);
                const int   oa = __shfl_xor(a4[hh][r], off);
                if (om > m4[hh][r] || (om == m4[hh][r] && oa < a4[hh][r])) {
                    m4[hh][r] = om; a4[hh][r] = oa;
                }
            }
    if (l15 == 0)
#pragma unroll
        for (int hh = 0; hh < 2; ++hh)
#pragma unroll
            for (int r = 0; r < 4; ++r) {
                const int row = rs * 32 + hh * 16 + l4 * 4 + r;
                wmax[row][cc] = m4[hh][r];
                warg[row][cc] = a4[hh][r];
            }
    __syncthreads();

    // E2a: combine 4 col-chunks -> row max over 320
    if (tid < BM) {
        float m = -3.4e38f; int c = 0x7fffffff;
#pragma unroll
        for (int q = 0; q < 4; ++q) {
            const float mq = wmax[tid][q];
            const int   cq = warg[tid][q];
            if (mq > m || (mq == m && cq < c)) { m = mq; c = cq; }
        }
        rmax_s[tid] = m;
        rarg_s[tid] = c;
    }
    __syncthreads();

    // E2b: candidate scan + exp + denominator partials
    float rm[2][4];
#pragma unroll
    for (int hh = 0; hh < 2; ++hh)
#pragma unroll
        for (int r = 0; r < 4; ++r) rm[hh][r] = rmax_s[rs * 32 + hh * 16 + l4 * 4 + r];
    float sden[2][4] = {{0.f,0.f,0.f,0.f},{0.f,0.f,0.f,0.f}};
#pragma unroll
    for (int n = 0; n < 5; ++n) {
        const int col = (nf0 + n) * 16 + l15;
#pragma unroll
        for (int hh = 0; hh < 2; ++hh)
#pragma unroll
            for (int r = 0; r < 4; ++r) {
                const float v = acc[hh][n][r];
                if (v > rm[hh][r] - MARGIN) {
                    const int row = rs * 32 + hh * 16 + l4 * 4 + r;
                    const int idx = atomicAdd(&cnt_s[row], 1);
                    if (idx < 16) list_s[row][idx] = col;
                }
                const float e = __expf(v - rm[hh][r]);
                acc[hh][n][r] = e;
                sden[hh][r] += e;
            }
    }
#pragma unroll
    for (int off = 8; off >= 1; off >>= 1)
#pragma unroll
        for (int hh = 0; hh < 2; ++hh)
#pragma unroll
            for (int r = 0; r < 4; ++r) sden[hh][r] += __shfl_xor(sden[hh][r], off);
    if (l15 == 0)
#pragma unroll
        for (int hh = 0; hh < 2; ++hh)
#pragma unroll
            for (int r = 0; r < 4; ++r)
                ssum[rs * 32 + hh * 16 + l4 * 4 + r][cc] = sden[hh][r];
    __syncthreads();

    // E3: single-candidate fast path; multi-candidate -> worklist
    if (tid < BM) {
        if (cnt_s[tid] <= 1) {
            code_s[tid] = rarg_s[tid];
        } else {
            const int wi = atomicAdd(&nwork_s, 1);
            work_s[wi] = tid;
        }
    }

    // E5: softmax column sums -> pacc[rs][v] (plain stores, disjoint (rs,cc) slots)
    float inv[2][4];
#pragma unroll
    for (int hh = 0; hh < 2; ++hh)
#pragma unroll
        for (int r = 0; r < 4; ++r) {
            const int row = rs * 32 + hh * 16 + l4 * 4 + r;
            inv[hh][r] = 1.f / (ssum[row][0] + ssum[row][1] + ssum[row][2] + ssum[row][3]);
        }
#pragma unroll
    for (int n = 0; n < 5; ++n) {
        float pc = 0.f;
#pragma unroll
        for (int hh = 0; hh < 2; ++hh)
#pragma unroll
            for (int r = 0; r < 4; ++r) pc += acc[hh][n][r] * inv[hh][r];
        pc += __shfl_xor(pc, 16);
        pc += __shfl_xor(pc, 32);
        if (l4 == 0) pacc[rs][(nf0 + n) * 16 + l15 - h * VSZ] = pc;
    }
    __syncthreads();

    // E4: fp32-exact refinement, one wave per pending row (float4, unrolled)
    const int nwork = nwork_s;
    for (int it = w; it < nwork; it += 8) {
        const int row  = work_s[it];
        const int grow = row0 + row;
        const int nc   = min(cnt_s[row], 16);
        const float4* xr = (const float4*)(x + (size_t)grow * KDIM);
        float bestv = -3.4e38f; int bestc = 0x7fffffff;
        for (int ci = 0; ci < nc; ++ci) {
            const int col = list_s[row][ci];
            const float4* wr = (const float4*)(W + (size_t)col * KDIM);
            float p = 0.f;
#pragma unroll
            for (int j = 0; j < 3; ++j) {
                const float4 xv2 = xr[lane + 64 * j];
                const float4 wv2 = wr[lane + 64 * j];
                p += xv2.x * wv2.x + xv2.y * wv2.y + xv2.z * wv2.z + xv2.w * wv2.w;
            }
#pragma unroll
            for (int off = 32; off >= 1; off >>= 1) p += __shfl_xor(p, off);
            p += b[col];
            if (p > bestv || (p == bestv && col < bestc)) { bestv = p; bestc = col; }
        }
        if (lane == 0) code_s[row] = bestc;
    }
    __syncthreads();

    // counts histogram in LDS
    if (tid < BM) atomicAdd(&cnt_f[code_s[tid] - h * VSZ], 1.f);

    // E7: gather xq for this block's 64 rows, its group's 128-dim half
#pragma unroll
    for (int u = 0; u < 4; ++u) {
        const int f   = tid + u * 512;      // float4 index 0..2047
        const int row = f >> 5;
        const int d4  = (f & 31) * 4;
        const int k   = code_s[row];        // global col = codebook row
        const float4 v = *(const float4*)(codebook + (size_t)k * DSZ + d4);
        *(float4*)(xq + (size_t)(row0 + row) * (GSZ * DSZ) + h * DSZ + d4) = v;
    }
    __syncthreads();

    // flush block-local sums with global atomics
    for (int i = tid; i < VSZ; i += 512) {
        atomicAdd(&accf[h * VSZ + i], cnt_f[i]);
        atomicAdd(&accf[NCOL + h * VSZ + i], pacc[0][i] + pacc[1][i]);
    }
}

// ---------------- perplexities + constant ----------------
__global__ __launch_bounds__(640) void finalize_k(const float* __restrict__ accf,
                                                  float* __restrict__ out_scalars) {
    __shared__ float se_c[GSZ], se_p[GSZ];
    const int t = threadIdx.x;
    if (t < GSZ) { se_c[t] = 0.f; se_p[t] = 0.f; }
    __syncthreads();
    const int g = t / VSZ;
    const float hp = accf[t]        * (1.f / (float)NROWS);
    const float ap = accf[NCOL + t] * (1.f / (float)NROWS);
    float tc = hp * logf(hp + 1e-7f);
    float tp = ap * logf(ap + 1e-7f);
#pragma unroll
    for (int off = 32; off >= 1; off >>= 1) {
        tc += __shfl_xor(tc, off);
        tp += __shfl_xor(tp, off);
    }
    if ((t & 63) == 0) { atomicAdd(&se_c[g], tc); atomicAdd(&se_p[g], tp); }
    __syncthreads();
    if (t == 0) {
        out_scalars[0] = (float)NCOL;
        out_scalars[1] = expf(-se_c[0]) + expf(-se_c[1]);
        out_scalars[2] = expf(-se_p[0]) + expf(-se_p[1]);
    }
}

extern "C" void kernel_launch(void* const* d_in, const int* in_sizes, int n_in,
                              void* d_out, int out_size, void* d_ws, size_t ws_size,
                              hipStream_t stream) {
    const float* x        = (const float*)d_in[0];
    const float* W        = (const float*)d_in[1];
    const float* b        = (const float*)d_in[2];
    const float* codebook = (const float*)d_in[3];
    float* out = (float*)d_out;

    short* Wb   = (short*)d_ws;                             //   983,040 B
    float* accf = (float*)((char*)d_ws + 983040);           //     5,120 B

    prep_w_k<<<dim3(240), dim3(256), 0, stream>>>(W, Wb, accf);
    fused_vq_k<<<dim3(NBLK), dim3(512), 0, stream>>>(Wb, x, W, b, codebook,
                                                     accf, out);
    finalize_k<<<dim3(1), dim3(640), 0, stream>>>(accf, out + XQ_TOTAL);
}

// Round 22
// 38.114 us; speedup vs baseline: 1.2826x; 1.2826x over previous
//
#include <hip/hip_runtime.h>
#include <hip/hip_bf16.h>

#define NROWS 8192      // B*T
#define KDIM  768       // F_IN
#define VSZ   320       // V
#define GSZ   2         // G
#define NCOL  640       // G*V
#define DSZ   128       // D
#define BM    64        // rows per block
#define NMT   (NROWS / BM)             // 128 M-tiles
#define NBLK  (NMT * 2)                // 256 blocks (x2 group-halves)
#define XQ_TOTAL (NROWS * GSZ * DSZ)   // 2097152
#define MARGIN 0.75f    // 12 sigma of bf16-dot pairwise error (sigma ~0.062)

typedef __attribute__((ext_vector_type(8))) short bf16x8;
typedef __attribute__((ext_vector_type(4))) float f32x4;

static __device__ __forceinline__ short f2bf(float f) {
    union { __hip_bfloat16 h; short s; } u;
    u.h = __float2bfloat16(f);   // round-to-nearest-even
    return u.s;
}

static __device__ __forceinline__ void gload_lds16(const void* g, void* l) {
    __builtin_amdgcn_global_load_lds(
        (const __attribute__((address_space(1))) void*)g,
        (__attribute__((address_space(3))) void*)l, 16, 0, 0);
}

// ---------------- prep: pack W only (frag-major bf16); zero accf ----------------
// Wb frag fid = (kb32*8 + hc)*5 + n: col = (hc*5+n)*16 + (l&15), k = kb32*32 + (l>>4)*8.
__global__ __launch_bounds__(256) void prep_w_k(const float* __restrict__ W,
                                                short* __restrict__ Wb,
                                                float* __restrict__ accf) {
    if (blockIdx.x == 0) {
        for (int i = threadIdx.x; i < 2 * NCOL; i += 256) accf[i] = 0.f;
    }
    const int id   = blockIdx.x * 256 + threadIdx.x;   // 0..61439
    const int lane = id & 63;
    const int f    = id >> 6;                           // 0..959
    const int n    = f % 5;
    const int t2   = f / 5;
    const int hc   = t2 & 7;
    const int kb   = t2 >> 3;                           // 0..23
    const int col  = (hc * 5 + n) * 16 + (lane & 15);
    const int k    = kb * 32 + (lane >> 4) * 8;
    const float4 a = *(const float4*)(W + (size_t)col * KDIM + k);
    const float4 c = *(const float4*)(W + (size_t)col * KDIM + k + 4);
    bf16x8 r;
    r[0] = f2bf(a.x); r[1] = f2bf(a.y); r[2] = f2bf(a.z); r[3] = f2bf(a.w);
    r[4] = f2bf(c.x); r[5] = f2bf(c.y); r[6] = f2bf(c.z); r[7] = f2bf(c.w);
    *(Wb + 0), *(bf16x8*)(Wb + (size_t)id * 8) = r;
}

// B staging for a 64-k step: 40 frags (rm 0..39; rm/20 = k-half, rm%20 = col-frag).
// 16 waves x 3 issues (uniform vmcnt); rm 32..39 double-issued (identical -> benign).
#define STAGEB(kb64, BUF) do {                                                 \
    _Pragma("unroll")                                                          \
    for (int j = 0; j < 3; ++j) {                                              \
        const int rm = (j == 0) ? w : (j == 1) ? (w + 16) : (32 + (w & 7));    \
        const int kf = rm / 20, rr = rm % 20;                                  \
        const short* srcp = Wb + ((size_t)((2 * (kb64) + kf) * 8 + hc0 + rr / 5) * 5 + rr % 5) * 512; \
        gload_lds16(srcp + lane * 8, (char*)(BUF) + 8192 + rm * 1024);         \
    }                                                                          \
} while (0)

// A staging: thread owns (arow = tid>>4, akk4 = (tid&15)*4) of the 64x64 A-step.
// Frag f = (arow>>4)*2 + (akk4>>5); in-frag lane = (arow&15) + 16*((akk4>>3)&3).
#define AWRITE(BUF, v) do {                                                    \
    const short s0 = f2bf((v).x), s1 = f2bf((v).y);                            \
    const short s2 = f2bf((v).z), s3 = f2bf((v).w);                            \
    const int lo = (s0 & 0xffff) | ((int)s1 << 16);                            \
    const int hi = (s2 & 0xffff) | ((int)s3 << 16);                            \
    *(int2*)((char*)(BUF) + a_off) = make_int2(lo, hi);                        \
} while (0)

// Wave tile 16x80 over 64 k: acc[5], 20 MFMA per step (r12 form).
#define COMPUTE(BUF) do {                                                      \
    const char* _bp = (const char*)(BUF);                                      \
    const bf16x8 a0 = *(const bf16x8*)(_bp + (rs * 2 + 0) * 1024 + lane * 16); \
    const bf16x8 a1 = *(const bf16x8*)(_bp + (rs * 2 + 1) * 1024 + lane * 16); \
    bf16x8 b0_[5], b1_[5];                                                     \
    _Pragma("unroll")                                                          \
    for (int n = 0; n < 5; ++n) {                                              \
        b0_[n] = *(const bf16x8*)(_bp + 8192 + (cc * 5 + n) * 1024 + lane * 16);      \
        b1_[n] = *(const bf16x8*)(_bp + 8192 + (20 + cc * 5 + n) * 1024 + lane * 16); \
    }                                                                          \
    _Pragma("unroll")                                                          \
    for (int n = 0; n < 5; ++n)                                                \
        acc[n] = __builtin_amdgcn_mfma_f32_16x16x32_bf16(a0, b0_[n], acc[n], 0, 0, 0); \
    _Pragma("unroll")                                                          \
    for (int n = 0; n < 5; ++n)                                                \
        acc[n] = __builtin_amdgcn_mfma_f32_16x16x32_bf16(a1, b1_[n], acc[n], 0, 0, 0); \
} while (0)

#define SYNC(N) do {                                                           \
    asm volatile("s_waitcnt vmcnt(" #N ") lgkmcnt(0)" ::: "memory");           \
    __builtin_amdgcn_sched_barrier(0);                                         \
    __builtin_amdgcn_s_barrier();                                              \
} while (0)

// Phase k: AWRITE A(k+1) (x(k+1) already landed -> no stall), shift, stage B(k+2),
// preload x(k+3), compute step k, SYNC(4) keeps {stage(k+2)x3, x(k+3)}.
#define PH(kk, BA, BS, BC) do {                                                \
    AWRITE(BA, xv1);                                                           \
    xv1 = xv2;                                                                 \
    STAGEB((kk) + 2, BS);                                                      \
    xv2 = *(const float4*)(xrow + ((kk) + 3) * 64);                            \
    COMPUTE(BC);                                                               \
    SYNC(4);                                                                   \
} while (0)

// ---------------- fused: 16-wave 3x48KB pipeline + in-kernel A-staging + epilogue ----------------
// grid 256 = 128 M-tiles x 2 groups (XCD-swizzled); 1024 threads = 16 waves (rs 0..3 x cc 0..3).
__global__ __launch_bounds__(1024, 4) void fused_vq_k(
    const short* __restrict__ Wb,
    const float* __restrict__ x, const float* __restrict__ W,
    const float* __restrict__ b, const float* __restrict__ codebook,
    float* __restrict__ accf, float* __restrict__ xq) {

    __shared__ __align__(16) char bufs[3][48 * 1024];   // 147,456 B
    __shared__ float pacc[4][VSZ];
    __shared__ float cnt_f[VSZ];
    __shared__ float wmax[BM][4];
    __shared__ int   warg[BM][4];
    __shared__ float ssum[BM][4];
    __shared__ float rmax_s[BM];
    __shared__ int   rarg_s[BM];
    __shared__ int   cnt_s[BM];
    __shared__ int   list_s[BM][16];
    __shared__ int   code_s[BM];
    __shared__ int   work_s[BM];
    __shared__ int   nwork_s;

    const int tid   = threadIdx.x;
    const int lane  = tid & 63;
    const int w     = tid >> 6;       // wave 0..15
    const int l15   = lane & 15;
    const int l4    = lane >> 4;
    const int sb    = ((int)blockIdx.x & 7) * (NBLK / 8) + ((int)blockIdx.x >> 3);
    const int mt    = sb >> 1;
    const int h     = sb & 1;         // group
    const int row0  = mt * BM;
    const int rs    = w >> 2;         // row-set 0..3 (16 rows each)
    const int cc    = w & 3;          // col-chunk 0..3 (80 cols)
    const int rbase = rs * 16;
    const int hc0   = h * 4;
    const int nf0   = h * 20 + cc * 5;

    // A-staging thread ownership (64 rows x 64 k per step; 1 float4/thread/step)
    const int arow  = tid >> 4;           // 0..63
    const int akk4  = (tid & 15) * 4;     // 0..60
    const int a_off = ((arow >> 4) * 2 + (akk4 >> 5)) * 1024 +
                      ((arow & 15) + 16 * ((akk4 >> 3) & 3)) * 16 + (akk4 & 4) * 2;
    const float* xrow = x + (size_t)(row0 + arow) * KDIM + akk4;

    for (int i = tid; i < VSZ; i += 1024) cnt_f[i] = 0.f;
    if (tid < BM) cnt_s[tid] = 0;
    if (tid == 0) nwork_s = 0;

    char* B0 = bufs[0];
    char* B1 = bufs[1];
    char* B2 = bufs[2];

    f32x4 acc[5];
#pragma unroll
    for (int n = 0; n < 5; ++n) acc[n] = (f32x4){0.f, 0.f, 0.f, 0.f};

    // ---- prologue: steps 0,1 staged; entering steady state {stage(1)x3, x(2)} ----
    float4 xv1, xv2;
    {
        const float4 xq0 = *(const float4*)(xrow);   // x(0)
        STAGEB(0, B0);                               // st0 x3
        AWRITE(B0, xq0);                             // waits x(0) -> vmcnt(3), st0 flies
        xv1 = *(const float4*)(xrow + 64);           // x(1)
        STAGEB(1, B1);                               // st1 x3
        xv2 = *(const float4*)(xrow + 128);          // x(2)
        SYNC(4);                                     // keep {st1 x3, x(2)}; x(1)+st0 drained
    }

    // ---- main: phases 0..8 as 3 static triples ----
#pragma unroll 1
    for (int t = 0; t < 3; ++t) {
        PH(3 * t + 0, B1, B2, B0);
        PH(3 * t + 1, B2, B0, B1);
        PH(3 * t + 2, B0, B1, B2);
    }
    // phase 9 (no x-preload: x(12) OOB)
    AWRITE(B1, xv1);          // A(10); x(10) landed
    xv1 = xv2;                // x(11)
    STAGEB(11, B2);
    COMPUTE(B0);              // step 9
    SYNC(4);                  // keep {x(11), st11 x3}; drain st10
    // tail
    AWRITE(B2, xv1);          // A(11); waits x(11) -> vmcnt(3), st11 flies
    COMPUTE(B1);              // step 10
    SYNC(0);                  // drain st11 + writes
    COMPUTE(B2);              // step 11

    // bias (zeros in this problem, kept exact)
#pragma unroll
    for (int n = 0; n < 5; ++n) {
        const float bv = b[(nf0 + n) * 16 + l15];
#pragma unroll
        for (int r = 0; r < 4; ++r) acc[n][r] += bv;
    }

    // E1: wave-local per-row max/argmax (rows rbase+l4*4+r, cols (nf0+n)*16+l15)
    float m4[4]; int a4[4];
#pragma unroll
    for (int r = 0; r < 4; ++r) { m4[r] = -3.4e38f; a4[r] = 0x7fffffff; }
#pragma unroll
    for (int n = 0; n < 5; ++n) {
        const int col = (nf0 + n) * 16 + l15;
#pragma unroll
        for (int r = 0; r < 4; ++r) {
            const float v = acc[n][r];
            if (v > m4[r]) { m4[r] = v; a4[r] = col; }
        }
    }
#pragma unroll
    for (int off = 8; off >= 1; off >>= 1)
#pragma unroll
        for (int r = 0; r < 4; ++r) {
            const float om = __shfl_xor(m4[r], off);
            const int   oa = __shfl_xor(a4[r], off);
            if (om > m4[r] || (om == m4[r] && oa < a4[r])) { m4[r] = om; a4[r] = oa; }
        }
    if (l15 == 0)
#pragma unroll
        for (int r = 0; r < 4; ++r) {
            const int row = rbase + l4 * 4 + r;
            wmax[row][cc] = m4[r];
            warg[row][cc] = a4[r];
        }
    __syncthreads();

    // E2a: combine 4 col-chunks -> row max over 320
    if (tid < BM) {
        float m = -3.4e38f; int c = 0x7fffffff;
#pragma unroll
        for (int q = 0; q < 4; ++q) {
            const float mq = wmax[tid][q];
            const int   cq = warg[tid][q];
            if (mq > m || (mq == m && cq < c)) { m = mq; c = cq; }
        }
        rmax_s[tid] = m;
        rarg_s[tid] = c;
    }
    __syncthreads();

    // E2b: candidate scan + exp + denominator partials
    float rm[4];
#pragma unroll
    for (int r = 0; r < 4; ++r) rm[r] = rmax_s[rbase + l4 * 4 + r];
    float sden[4] = {0.f, 0.f, 0.f, 0.f};
#pragma unroll
    for (int n = 0; n < 5; ++n) {
        const int col = (nf0 + n) * 16 + l15;
#pragma unroll
        for (int r = 0; r < 4; ++r) {
            const float v = acc[n][r];
            if (v > rm[r] - MARGIN) {
                const int row = rbase + l4 * 4 + r;
                const int idx = atomicAdd(&cnt_s[row], 1);
                if (idx < 16) list_s[row][idx] = col;
            }
            const float e = __expf(v - rm[r]);
            acc[n][r] = e;
            sden[r] += e;
        }
    }
#pragma unroll
    for (int off = 8; off >= 1; off >>= 1)
#pragma unroll
        for (int r = 0; r < 4; ++r) sden[r] += __shfl_xor(sden[r], off);
    if (l15 == 0)
#pragma unroll
        for (int r = 0; r < 4; ++r) ssum[rbase + l4 * 4 + r][cc] = sden[r];
    __syncthreads();

    // E3: single-candidate fast path; multi-candidate -> worklist
    if (tid < BM) {
        if (cnt_s[tid] <= 1) {
            code_s[tid] = rarg_s[tid];
        } else {
            const int wi = atomicAdd(&nwork_s, 1);
            work_s[wi] = tid;
        }
    }

    // E5: softmax column sums -> pacc[rs][v] (plain stores, disjoint (rs,cc) slots)
    float inv[4];
#pragma unroll
    for (int r = 0; r < 4; ++r) {
        const int row = rbase + l4 * 4 + r;
        inv[r] = 1.f / (ssum[row][0] + ssum[row][1] + ssum[row][2] + ssum[row][3]);
    }
#pragma unroll
    for (int n = 0; n < 5; ++n) {
        float pc = 0.f;
#pragma unroll
        for (int r = 0; r < 4; ++r) pc += acc[n][r] * inv[r];
        pc += __shfl_xor(pc, 16);
        pc += __shfl_xor(pc, 32);
        if (l4 == 0) pacc[rs][(nf0 + n) * 16 + l15 - h * VSZ] = pc;
    }
    __syncthreads();

    // E4: fp32-exact refinement, one wave per pending row (float4, unrolled)
    const int nwork = nwork_s;
    for (int it = w; it < nwork; it += 16) {
        const int row  = work_s[it];
        const int grow = row0 + row;
        const int nc   = min(cnt_s[row], 16);
        const float4* xr = (const float4*)(x + (size_t)grow * KDIM);
        float bestv = -3.4e38f; int bestc = 0x7fffffff;
        for (int ci = 0; ci < nc; ++ci) {
            const int col = list_s[row][ci];
            const float4* wr = (const float4*)(W + (size_t)col * KDIM);
            float p = 0.f;
#pragma unroll
            for (int j = 0; j < 3; ++j) {
                const float4 xa = xr[lane + 64 * j];
                const float4 wa = wr[lane + 64 * j];
                p += xa.x * wa.x + xa.y * wa.y + xa.z * wa.z + xa.w * wa.w;
            }
#pragma unroll
            for (int off = 32; off >= 1; off >>= 1) p += __shfl_xor(p, off);
            p += b[col];
            if (p > bestv || (p == bestv && col < bestc)) { bestv = p; bestc = col; }
        }
        if (lane == 0) code_s[row] = bestc;
    }
    __syncthreads();

    // counts histogram in LDS
    if (tid < BM) atomicAdd(&cnt_f[code_s[tid] - h * VSZ], 1.f);

    // E7: gather xq for this block's 64 rows, its group's 128-dim half
#pragma unroll
    for (int u = 0; u < 2; ++u) {
        const int f   = tid + u * 1024;     // float4 index 0..2047
        const int row = f >> 5;
        const int d4  = (f & 31) * 4;
        const int k   = code_s[row];        // global col = codebook row
        const float4 v = *(const float4*)(codebook + (size_t)k * DSZ + d4);
        *(float4*)(xq + (size_t)(row0 + row) * (GSZ * DSZ) + h * DSZ + d4) = v;
    }
    __syncthreads();

    // flush block-local sums with global atomics
    for (int i = tid; i < VSZ; i += 1024) {
        atomicAdd(&accf[h * VSZ + i], cnt_f[i]);
        atomicAdd(&accf[NCOL + h * VSZ + i],
                  pacc[0][i] + pacc[1][i] + pacc[2][i] + pacc[3][i]);
    }
}

// ---------------- perplexities + constant ----------------
__global__ __launch_bounds__(640) void finalize_k(const float* __restrict__ accf,
                                                  float* __restrict__ out_scalars) {
    __shared__ float se_c[GSZ], se_p[GSZ];
    const int t = threadIdx.x;
    if (t < GSZ) { se_c[t] = 0.f; se_p[t] = 0.f; }
    __syncthreads();
    const int g = t / VSZ;
    const float hp = accf[t]        * (1.f / (float)NROWS);
    const float ap = accf[NCOL + t] * (1.f / (float)NROWS);
    float tc = hp * logf(hp + 1e-7f);
    float tp = ap * logf(ap + 1e-7f);
#pragma unroll
    for (int off = 32; off >= 1; off >>= 1) {
        tc += __shfl_xor(tc, off);
        tp += __shfl_xor(tp, off);
    }
    if ((t & 63) == 0) { atomicAdd(&se_c[g], tc); atomicAdd(&se_p[g], tp); }
    __syncthreads();
    if (t == 0) {
        out_scalars[0] = (float)NCOL;
        out_scalars[1] = expf(-se_c[0]) + expf(-se_c[1]);
        out_scalars[2] = expf(-se_p[0]) + expf(-se_p[1]);
    }
}

extern "C" void kernel_launch(void* const* d_in, const int* in_sizes, int n_in,
                              void* d_out, int out_size, void* d_ws, size_t ws_size,
                              hipStream_t stream) {
    const float* x        = (const float*)d_in[0];
    const float* W        = (const float*)d_in[1];
    const float* b        = (const float*)d_in[2];
    const float* codebook = (const float*)d_in[3];
    float* out = (float*)d_out;

    short* Wb   = (short*)d_ws;                             //   983,040 B
    float* accf = (float*)((char*)d_ws + 983040);           //     5,120 B

    prep_w_k<<<dim3(240), dim3(256), 0, stream>>>(W, Wb, accf);
    fused_vq_k<<<dim3(NBLK), dim3(1024), 0, stream>>>(Wb, x, W, b, codebook,
                                                      accf, out);
    finalize_k<<<dim3(1), dim3(640), 0, stream>>>(accf, out + XQ_TOTAL);
}

// Round 23
// 36.933 us; speedup vs baseline: 1.3236x; 1.0320x over previous
//
#include <hip/hip_runtime.h>
#include <hip/hip_bf16.h>

#define NROWS 8192      // B*T
#define KDIM  768       // F_IN
#define VSZ   320       // V
#define GSZ   2         // G
#define NCOL  640       // G*V
#define DSZ   128       // D
#define BM    64        // rows per block
#define NMT   (NROWS / BM)             // 128 M-tiles
#define NBLK  (NMT * 2)                // 256 blocks (x2 group-halves)
#define XQ_TOTAL (NROWS * GSZ * DSZ)   // 2097152
#define MARGIN 0.75f    // 12 sigma of bf16-dot pairwise error (sigma ~0.062)
#define NSHARD 8                       // accumulator shards (one per XCD)

typedef __attribute__((ext_vector_type(8))) short bf16x8;
typedef __attribute__((ext_vector_type(4))) float f32x4;

static __device__ __forceinline__ short f2bf(float f) {
    union { __hip_bfloat16 h; short s; } u;
    u.h = __float2bfloat16(f);   // round-to-nearest-even
    return u.s;
}

static __device__ __forceinline__ void gload_lds16(const void* g, void* l) {
    __builtin_amdgcn_global_load_lds(
        (const __attribute__((address_space(1))) void*)g,
        (__attribute__((address_space(3))) void*)l, 16, 0, 0);
}

// ---------------- prep: pack W only (frag-major bf16); zero sharded accf ----------------
// Wb frag fid = (kb32*8 + hc)*5 + n: col = (hc*5+n)*16 + (l&15), k = kb32*32 + (l>>4)*8.
__global__ __launch_bounds__(256) void prep_w_k(const float* __restrict__ W,
                                                short* __restrict__ Wb,
                                                float* __restrict__ accf) {
    if (blockIdx.x < 20) {   // zero 8*2560 floats = 20 blocks x 1024... (20*256*2 = 10240)
        const int i = blockIdx.x * 256 + threadIdx.x;
        accf[i] = 0.f;
        accf[i + 5120] = 0.f;
    }
    const int id   = blockIdx.x * 256 + threadIdx.x;   // 0..61439
    const int lane = id & 63;
    const int f    = id >> 6;                           // 0..959
    const int n    = f % 5;
    const int t2   = f / 5;
    const int hc   = t2 & 7;
    const int kb   = t2 >> 3;                           // 0..23
    const int col  = (hc * 5 + n) * 16 + (lane & 15);
    const int k    = kb * 32 + (lane >> 4) * 8;
    const float4 a = *(const float4*)(W + (size_t)col * KDIM + k);
    const float4 c = *(const float4*)(W + (size_t)col * KDIM + k + 4);
    bf16x8 r;
    r[0] = f2bf(a.x); r[1] = f2bf(a.y); r[2] = f2bf(a.z); r[3] = f2bf(a.w);
    r[4] = f2bf(c.x); r[5] = f2bf(c.y); r[6] = f2bf(c.z); r[7] = f2bf(c.w);
    *(bf16x8*)(Wb + (size_t)id * 8) = r;
}

// B staging for a 64-k step: 40 frags (rm 0..39; rm/20 = k-half, rm%20 = col-frag).
// 16 waves x 3 issues (uniform vmcnt); rm 32..39 double-issued (identical -> benign).
#define STAGEB(kb64, BUF) do {                                                 \
    _Pragma("unroll")                                                          \
    for (int j = 0; j < 3; ++j) {                                              \
        const int rm = (j == 0) ? w : (j == 1) ? (w + 16) : (32 + (w & 7));    \
        const int kf = rm / 20, rr = rm % 20;                                  \
        const short* srcp = Wb + ((size_t)((2 * (kb64) + kf) * 8 + hc0 + rr / 5) * 5 + rr % 5) * 512; \
        gload_lds16(srcp + lane * 8, (char*)(BUF) + 8192 + rm * 1024);         \
    }                                                                          \
} while (0)

// A staging: thread owns (arow = tid>>4, akk4 = (tid&15)*4) of the 64x64 A-step.
#define AWRITE(BUF, v) do {                                                    \
    const short s0 = f2bf((v).x), s1 = f2bf((v).y);                            \
    const short s2 = f2bf((v).z), s3 = f2bf((v).w);                            \
    const int lo = (s0 & 0xffff) | ((int)s1 << 16);                            \
    const int hi = (s2 & 0xffff) | ((int)s3 << 16);                            \
    *(int2*)((char*)(BUF) + a_off) = make_int2(lo, hi);                        \
} while (0)

// Wave tile 16x80 over 64 k: acc[5], 20 MFMA per step.
#define COMPUTE(BUF) do {                                                      \
    const char* _bp = (const char*)(BUF);                                      \
    const bf16x8 a0 = *(const bf16x8*)(_bp + (rs * 2 + 0) * 1024 + lane * 16); \
    const bf16x8 a1 = *(const bf16x8*)(_bp + (rs * 2 + 1) * 1024 + lane * 16); \
    bf16x8 b0_[5], b1_[5];                                                     \
    _Pragma("unroll")                                                          \
    for (int n = 0; n < 5; ++n) {                                              \
        b0_[n] = *(const bf16x8*)(_bp + 8192 + (cc * 5 + n) * 1024 + lane * 16);      \
        b1_[n] = *(const bf16x8*)(_bp + 8192 + (20 + cc * 5 + n) * 1024 + lane * 16); \
    }                                                                          \
    _Pragma("unroll")                                                          \
    for (int n = 0; n < 5; ++n)                                                \
        acc[n] = __builtin_amdgcn_mfma_f32_16x16x32_bf16(a0, b0_[n], acc[n], 0, 0, 0); \
    _Pragma("unroll")                                                          \
    for (int n = 0; n < 5; ++n)                                                \
        acc[n] = __builtin_amdgcn_mfma_f32_16x16x32_bf16(a1, b1_[n], acc[n], 0, 0, 0); \
} while (0)

#define SYNC(N) do {                                                           \
    asm volatile("s_waitcnt vmcnt(" #N ") lgkmcnt(0)" ::: "memory");           \
    __builtin_amdgcn_sched_barrier(0);                                         \
    __builtin_amdgcn_s_barrier();                                              \
} while (0)

// Phase k: AWRITE A(k+1) (x(k+1) already landed -> no stall), shift, stage B(k+2),
// preload x(k+3), compute step k, SYNC(4) keeps {stage(k+2)x3, x(k+3)}.
#define PH(kk, BA, BS, BC) do {                                                \
    AWRITE(BA, xv1);                                                           \
    xv1 = xv2;                                                                 \
    STAGEB((kk) + 2, BS);                                                      \
    xv2 = *(const float4*)(xrow + ((kk) + 3) * 64);                            \
    COMPUTE(BC);                                                               \
    SYNC(4);                                                                   \
} while (0)

// ---------------- fused: 16-wave 3x48KB pipeline + in-kernel A-staging + epilogue ----------------
// grid 256 = 128 M-tiles x 2 groups (XCD-swizzled); 1024 threads = 16 waves (rs x cc).
__global__ __launch_bounds__(1024, 4) void fused_vq_k(
    const short* __restrict__ Wb,
    const float* __restrict__ x, const float* __restrict__ W,
    const float* __restrict__ b, const float* __restrict__ codebook,
    float* __restrict__ accf, float* __restrict__ xq) {

    __shared__ __align__(16) char bufs[3][48 * 1024];   // 147,456 B
    __shared__ float pacc[4][VSZ];
    __shared__ float cnt_f[VSZ];
    __shared__ float wmax[BM][4];
    __shared__ int   warg[BM][4];
    __shared__ float ssum[BM][4];
    __shared__ float rmax_s[BM];
    __shared__ int   rarg_s[BM];
    __shared__ int   cnt_s[BM];
    __shared__ int   list_s[BM][16];
    __shared__ int   code_s[BM];
    __shared__ int   work_s[BM];
    __shared__ int   nwork_s;

    const int tid   = threadIdx.x;
    const int lane  = tid & 63;
    const int w     = tid >> 6;       // wave 0..15
    const int l15   = lane & 15;
    const int l4    = lane >> 4;
    const int xcd   = (int)blockIdx.x & 7;
    const int sb    = xcd * (NBLK / 8) + ((int)blockIdx.x >> 3);
    const int mt    = sb >> 1;
    const int h     = sb & 1;         // group
    const int row0  = mt * BM;
    const int rs    = w >> 2;         // row-set 0..3 (16 rows each)
    const int cc    = w & 3;          // col-chunk 0..3 (80 cols)
    const int rbase = rs * 16;
    const int hc0   = h * 4;
    const int nf0   = h * 20 + cc * 5;

    // XCD-local accumulator shard
    float* accs = accf + (size_t)xcd * (2 * NCOL);

    // A-staging thread ownership (64 rows x 64 k per step; 1 float4/thread/step)
    const int arow  = tid >> 4;           // 0..63
    const int akk4  = (tid & 15) * 4;     // 0..60
    const int a_off = ((arow >> 4) * 2 + (akk4 >> 5)) * 1024 +
                      ((arow & 15) + 16 * ((akk4 >> 3) & 3)) * 16 + (akk4 & 4) * 2;
    const float* xrow = x + (size_t)(row0 + arow) * KDIM + akk4;

    for (int i = tid; i < VSZ; i += 1024) cnt_f[i] = 0.f;
    if (tid < BM) cnt_s[tid] = 0;
    if (tid == 0) nwork_s = 0;

    char* B0 = bufs[0];
    char* B1 = bufs[1];
    char* B2 = bufs[2];

    f32x4 acc[5];
#pragma unroll
    for (int n = 0; n < 5; ++n) acc[n] = (f32x4){0.f, 0.f, 0.f, 0.f};

    // ---- prologue: steps 0,1 staged; entering steady state {stage(1)x3, x(2)} ----
    float4 xv1, xv2;
    {
        const float4 xq0 = *(const float4*)(xrow);   // x(0)
        STAGEB(0, B0);                               // st0 x3
        AWRITE(B0, xq0);                             // waits x(0) -> vmcnt(3), st0 flies
        xv1 = *(const float4*)(xrow + 64);           // x(1)
        STAGEB(1, B1);                               // st1 x3
        xv2 = *(const float4*)(xrow + 128);          // x(2)
        SYNC(4);                                     // keep {st1 x3, x(2)}
    }

    // ---- main: phases 0..8 as 3 static triples ----
#pragma unroll 1
    for (int t = 0; t < 3; ++t) {
        PH(3 * t + 0, B1, B2, B0);
        PH(3 * t + 1, B2, B0, B1);
        PH(3 * t + 2, B0, B1, B2);
    }
    // phase 9 (no x-preload: x(12) OOB)
    AWRITE(B1, xv1);          // A(10); x(10) landed
    xv1 = xv2;                // x(11)
    STAGEB(11, B2);
    COMPUTE(B0);              // step 9
    SYNC(4);                  // keep {x(11), st11 x3}
    // tail
    AWRITE(B2, xv1);          // A(11); waits x(11) -> vmcnt(3), st11 flies
    COMPUTE(B1);              // step 10
    SYNC(0);                  // drain st11 + writes
    COMPUTE(B2);              // step 11

    // bias (zeros in this problem, kept exact)
#pragma unroll
    for (int n = 0; n < 5; ++n) {
        const float bv = b[(nf0 + n) * 16 + l15];
#pragma unroll
        for (int r = 0; r < 4; ++r) acc[n][r] += bv;
    }

    // E1: wave-local per-row max/argmax (rows rbase+l4*4+r, cols (nf0+n)*16+l15)
    float m4[4]; int a4[4];
#pragma unroll
    for (int r = 0; r < 4; ++r) { m4[r] = -3.4e38f; a4[r] = 0x7fffffff; }
#pragma unroll
    for (int n = 0; n < 5; ++n) {
        const int col = (nf0 + n) * 16 + l15;
#pragma unroll
        for (int r = 0; r < 4; ++r) {
            const float v = acc[n][r];
            if (v > m4[r]) { m4[r] = v; a4[r] = col; }
        }
    }
#pragma unroll
    for (int off = 8; off >= 1; off >>= 1)
#pragma unroll
        for (int r = 0; r < 4; ++r) {
            const float om = __shfl_xor(m4[r], off);
            const int   oa = __shfl_xor(a4[r], off);
            if (om > m4[r] || (om == m4[r] && oa < a4[r])) { m4[r] = om; a4[r] = oa; }
        }
    if (l15 == 0)
#pragma unroll
        for (int r = 0; r < 4; ++r) {
            const int row = rbase + l4 * 4 + r;
            wmax[row][cc] = m4[r];
            warg[row][cc] = a4[r];
        }
    __syncthreads();

    // E2a: combine 4 col-chunks -> row max over 320
    if (tid < BM) {
        float m = -3.4e38f; int c = 0x7fffffff;
#pragma unroll
        for (int q = 0; q < 4; ++q) {
            const float mq = wmax[tid][q];
            const int   cq = warg[tid][q];
            if (mq > m || (mq == m && cq < c)) { m = mq; c = cq; }
        }
        rmax_s[tid] = m;
        rarg_s[tid] = c;
    }
    __syncthreads();

    // E2b: candidate scan + exp + denominator partials
    float rm[4];
#pragma unroll
    for (int r = 0; r < 4; ++r) rm[r] = rmax_s[rbase + l4 * 4 + r];
    float sden[4] = {0.f, 0.f, 0.f, 0.f};
#pragma unroll
    for (int n = 0; n < 5; ++n) {
        const int col = (nf0 + n) * 16 + l15;
#pragma unroll
        for (int r = 0; r < 4; ++r) {
            const float v = acc[n][r];
            if (v > rm[r] - MARGIN) {
                const int row = rbase + l4 * 4 + r;
                const int idx = atomicAdd(&cnt_s[row], 1);
                if (idx < 16) list_s[row][idx] = col;
            }
            const float e = __expf(v - rm[r]);
            acc[n][r] = e;
            sden[r] += e;
        }
    }
#pragma unroll
    for (int off = 8; off >= 1; off >>= 1)
#pragma unroll
        for (int r = 0; r < 4; ++r) sden[r] += __shfl_xor(sden[r], off);
    if (l15 == 0)
#pragma unroll
        for (int r = 0; r < 4; ++r) ssum[rbase + l4 * 4 + r][cc] = sden[r];
    __syncthreads();

    // E3: single-candidate fast path; multi-candidate -> worklist
    if (tid < BM) {
        if (cnt_s[tid] <= 1) {
            code_s[tid] = rarg_s[tid];
        } else {
            const int wi = atomicAdd(&nwork_s, 1);
            work_s[wi] = tid;
        }
    }

    // E5: softmax column sums -> pacc[rs][v] (plain stores, disjoint (rs,cc) slots)
    float inv[4];
#pragma unroll
    for (int r = 0; r < 4; ++r) {
        const int row = rbase + l4 * 4 + r;
        inv[r] = 1.f / (ssum[row][0] + ssum[row][1] + ssum[row][2] + ssum[row][3]);
    }
#pragma unroll
    for (int n = 0; n < 5; ++n) {
        float pc = 0.f;
#pragma unroll
        for (int r = 0; r < 4; ++r) pc += acc[n][r] * inv[r];
        pc += __shfl_xor(pc, 16);
        pc += __shfl_xor(pc, 32);
        if (l4 == 0) pacc[rs][(nf0 + n) * 16 + l15 - h * VSZ] = pc;
    }
    __syncthreads();

    // E4: fp32-exact refinement, one wave per pending row (float4, unrolled)
    const int nwork = nwork_s;
    for (int it = w; it < nwork; it += 16) {
        const int row  = work_s[it];
        const int grow = row0 + row;
        const int nc   = min(cnt_s[row], 16);
        const float4* xr = (const float4*)(x + (size_t)grow * KDIM);
        float bestv = -3.4e38f; int bestc = 0x7fffffff;
        for (int ci = 0; ci < nc; ++ci) {
            const int col = list_s[row][ci];
            const float4* wr = (const float4*)(W + (size_t)col * KDIM);
            float p = 0.f;
#pragma unroll
            for (int j = 0; j < 3; ++j) {
                const float4 xa = xr[lane + 64 * j];
                const float4 wa = wr[lane + 64 * j];
                p += xa.x * wa.x + xa.y * wa.y + xa.z * wa.z + xa.w * wa.w;
            }
#pragma unroll
            for (int off = 32; off >= 1; off >>= 1) p += __shfl_xor(p, off);
            p += b[col];
            if (p > bestv || (p == bestv && col < bestc)) { bestv = p; bestc = col; }
        }
        if (lane == 0) code_s[row] = bestc;
    }
    __syncthreads();

    // counts histogram in LDS
    if (tid < BM) atomicAdd(&cnt_f[code_s[tid] - h * VSZ], 1.f);

    // E7: gather xq for this block's 64 rows, its group's 128-dim half
#pragma unroll
    for (int u = 0; u < 2; ++u) {
        const int f   = tid + u * 1024;     // float4 index 0..2047
        const int row = f >> 5;
        const int d4  = (f & 31) * 4;
        const int k   = code_s[row];        // global col = codebook row
        const float4 v = *(const float4*)(codebook + (size_t)k * DSZ + d4);
        *(float4*)(xq + (size_t)(row0 + row) * (GSZ * DSZ) + h * DSZ + d4) = v;
    }
    __syncthreads();

    // flush block-local sums to the XCD-local accumulator shard (8x less contention,
    // no cross-XCD coherence round-trip)
    for (int i = tid; i < VSZ; i += 1024) {
        atomicAdd(&accs[h * VSZ + i], cnt_f[i]);
        atomicAdd(&accs[NCOL + h * VSZ + i],
                  pacc[0][i] + pacc[1][i] + pacc[2][i] + pacc[3][i]);
    }
}

// ---------------- perplexities + constant (sums 8 shards) ----------------
__global__ __launch_bounds__(640) void finalize_k(const float* __restrict__ accf,
                                                  float* __restrict__ out_scalars) {
    __shared__ float se_c[GSZ], se_p[GSZ];
    const int t = threadIdx.x;
    if (t < GSZ) { se_c[t] = 0.f; se_p[t] = 0.f; }
    __syncthreads();
    const int g = t / VSZ;
    float sc = 0.f, sp = 0.f;
#pragma unroll
    for (int s = 0; s < NSHARD; ++s) {
        sc += accf[(size_t)s * (2 * NCOL) + t];
        sp += accf[(size_t)s * (2 * NCOL) + NCOL + t];
    }
    const float hp = sc * (1.f / (float)NROWS);
    const float ap = sp * (1.f / (float)NROWS);
    float tc = hp * logf(hp + 1e-7f);
    float tp = ap * logf(ap + 1e-7f);
#pragma unroll
    for (int off = 32; off >= 1; off >>= 1) {
        tc += __shfl_xor(tc, off);
        tp += __shfl_xor(tp, off);
    }
    if ((t & 63) == 0) { atomicAdd(&se_c[g], tc); atomicAdd(&se_p[g], tp); }
    __syncthreads();
    if (t == 0) {
        out_scalars[0] = (float)NCOL;
        out_scalars[1] = expf(-se_c[0]) + expf(-se_c[1]);
        out_scalars[2] = expf(-se_p[0]) + expf(-se_p[1]);
    }
}

extern "C" void kernel_launch(void* const* d_in, const int* in_sizes, int n_in,
                              void* d_out, int out_size, void* d_ws, size_t ws_size,
                              hipStream_t stream) {
    const float* x        = (const float*)d_in[0];
    const float* W        = (const float*)d_in[1];
    const float* b        = (const float*)d_in[2];
    const float* codebook = (const float*)d_in[3];
    float* out = (float*)d_out;

    short* Wb   = (short*)d_ws;                             //   983,040 B
    float* accf = (float*)((char*)d_ws + 983040);           // 8*1280*4 = 40,960 B

    prep_w_k<<<dim3(240), dim3(256), 0, stream>>>(W, Wb, accf);
    fused_vq_k<<<dim3(NBLK), dim3(1024), 0, stream>>>(Wb, x, W, b, codebook,
                                                      accf, out);
    finalize_k<<<dim3(1), dim3(640), 0, stream>>>(accf, out + XQ_TOTAL);
}